// Round 1
// 264.460 us; speedup vs baseline: 1.0526x; 1.0526x over previous
//
#include <hip/hip_runtime.h>
#include <cmath>

// R5: barrier-free wave-autonomous gram kernel.
// R4 counters: gram 116 us, VALUBusy 26%, HBM 18%, Occupancy 19% -> both
// pipes idle => latency/sync-bound (FMA floor 18 us, HBM floor ~37 us).
// The block-wide LDS double buffer serialized 4 waves on __syncthreads +
// vmcnt drain every chunk. Now each 64-lane wave owns a private 8 KB LDS
// stage (same-wave DS ops are pipe-ordered on CDNA -> NO barrier in the
// main loop), 512-col stripe/wave, next chunk's global loads issued in
// registers under the 768-FMA phase. XOR-swizzled col-major layout
// addr(c,rg)=32c+4*(((c>>2)^rg)&7): b128 reads have 16 unique addrs
// (4x tk-broadcast) spread over 8 bank groups -> conflict-free; writes
// are exactly 8 lanes/4-bank-group -> optimal.
// Epilogue: the 2 waves of a block combine through LDS (single barrier),
// store CONTIGUOUS [block][800] fp32 partials (b128) -> kills the 46 MB
// scattered-write amplification. reduce reads coalesced rows + fp64
// atomicAdd. sinkhorn absorbs finalize (1 block, 6 waves) -> 4 dispatches.
// NOTE: no min-waves clause in __launch_bounds__ (R3 lesson: (256,4)
// clamped VGPRs and spilled accumulators, 9x regression).

#define TPB 128                      // 2 independent waves per block
#define CCH 64                       // columns staged per chunk per wave
#define NCH 8                        // chunks per wave stripe
#define STRIPE (CCH * NCH)           // 512 cols per wave
#define COLS_PER_BLOCK (2 * STRIPE)  // 1024 cols per block
#define NSTEP 60

struct EpsList { float e[NSTEP]; };

struct GramArgs {
  const float* x0; const float* y0;
  const float* x1; const float* y1;
  const float* x2; const float* y2;
  int M0, M1, M2;
  int bs1, bs2, bsTot;
  float* partial;     // [block][800] contiguous fp32
  double* finalG;     // [3][800]
  int atomicMode;
};

// float4 holding rows 4rg..4rg+3 (rg 0..3 = x, 4..7 = y) of column c,
// XOR-swizzled so reads AND writes are bank-optimal.
__device__ __forceinline__ float* ldsAt(float* buf, int c, int rg) {
  return buf + c * 32 + 4 * (((c >> 2) ^ rg) & 7);
}

__global__ __launch_bounds__(TPB) void gram_kernel(GramArgs A) {
  __shared__ __align__(16) float sE[2][2048];   // 8 KB per wave, private

  const int bid = blockIdx.x;
  int p, lb;
  if (bid >= A.bs2)      { p = 2; lb = bid - A.bs2; }
  else if (bid >= A.bs1) { p = 1; lb = bid - A.bs1; }
  else                   { p = 0; lb = bid; }
  const float* X = (p == 0) ? A.x0 : (p == 1) ? A.x1 : A.x2;
  const float* Y = (p == 0) ? A.y0 : (p == 1) ? A.y1 : A.y2;
  const int M    = (p == 0) ? A.M0 : (p == 1) ? A.M1 : A.M2;

  const int t    = threadIdx.x;
  const int w    = t >> 6;        // wave in block
  const int lane = t & 63;
  float* buf = sE[w];

  // loader mapping: lane (h, cl) owns rows 4h..4h+3 of x and y, cols 4cl..4cl+3
  const int h  = lane >> 4;
  const int cl = lane & 15;
  // FMA mapping: 16 (4x4) tiles x 4 column-slices
  const int s    = lane & 3;
  const int tile = lane >> 2;
  const int ti   = tile >> 2;
  const int tk   = tile & 3;

  const size_t colbase = (size_t)(2 * lb + w) * STRIPE;
  const float* px = X + (size_t)(4 * h) * M + colbase + 4 * cl;
  const float* py = Y + (size_t)(4 * h) * M + colbase + 4 * cl;

  float4 LX[4], LY[4];
  #pragma unroll
  for (int q = 0; q < 4; ++q) {
    LX[q] = *reinterpret_cast<const float4*>(px + (size_t)q * M);
    LY[q] = *reinterpret_cast<const float4*>(py + (size_t)q * M);
  }

  float axy[4][4] = {}, axx[4][4] = {}, ayy[4][4] = {};
  float zx[4] = {}, zy[4] = {};

  #pragma unroll 1
  for (int ch = 0; ch < NCH; ++ch) {
    // ---- stage: exp + wave-private LDS transpose write ----
    #pragma unroll
    for (int j = 0; j < 4; ++j) {
      const int c = 4 * cl + j;
      const float e0 = __expf(((const float*)&LX[0])[j]);
      const float e1 = __expf(((const float*)&LX[1])[j]);
      const float e2 = __expf(((const float*)&LX[2])[j]);
      const float e3 = __expf(((const float*)&LX[3])[j]);
      zx[0] += e0; zx[1] += e1; zx[2] += e2; zx[3] += e3;
      *reinterpret_cast<float4*>(ldsAt(buf, c, h)) = make_float4(e0, e1, e2, e3);
      const float f0 = __expf(((const float*)&LY[0])[j]);
      const float f1 = __expf(((const float*)&LY[1])[j]);
      const float f2 = __expf(((const float*)&LY[2])[j]);
      const float f3 = __expf(((const float*)&LY[3])[j]);
      zy[0] += f0; zy[1] += f1; zy[2] += f2; zy[3] += f3;
      *reinterpret_cast<float4*>(ldsAt(buf, c, 4 + h)) = make_float4(f0, f1, f2, f3);
    }
    // ---- issue next chunk's global loads; latency hides under FMAs ----
    if (ch + 1 < NCH) {
      const size_t o = (size_t)(ch + 1) * CCH;
      #pragma unroll
      for (int q = 0; q < 4; ++q) {
        LX[q] = *reinterpret_cast<const float4*>(px + (size_t)q * M + o);
        LY[q] = *reinterpret_cast<const float4*>(py + (size_t)q * M + o);
      }
    }
    __builtin_amdgcn_sched_barrier(0);   // keep writes above reads
    // ---- FMA phase: 64 conflict-free b128 reads + 768 FMAs ----
    #pragma unroll
    for (int it = 0; it < 16; ++it) {
      const int c = 16 * s + it;
      const float4 xi = *reinterpret_cast<const float4*>(ldsAt(buf, c, ti));
      const float4 xk = *reinterpret_cast<const float4*>(ldsAt(buf, c, tk));
      const float4 yi = *reinterpret_cast<const float4*>(ldsAt(buf, c, 4 + ti));
      const float4 yk = *reinterpret_cast<const float4*>(ldsAt(buf, c, 4 + tk));
      const float xiA[4] = {xi.x, xi.y, xi.z, xi.w};
      const float xkA[4] = {xk.x, xk.y, xk.z, xk.w};
      const float yiA[4] = {yi.x, yi.y, yi.z, yi.w};
      const float ykA[4] = {yk.x, yk.y, yk.z, yk.w};
      #pragma unroll
      for (int r = 0; r < 4; ++r) {
        #pragma unroll
        for (int u = 0; u < 4; ++u) {
          axy[r][u] = fmaf(xiA[r], ykA[u], axy[r][u]);
          axx[r][u] = fmaf(xiA[r], xkA[u], axx[r][u]);
          ayy[r][u] = fmaf(yiA[r], ykA[u], ayy[r][u]);
        }
      }
    }
    __builtin_amdgcn_sched_barrier(0);   // keep reads above next stage's writes
  }

  // ---- reduce over the 4 column-slices (lane bits 0..1) ----
  #pragma unroll
  for (int r = 0; r < 4; ++r) {
    #pragma unroll
    for (int u = 0; u < 4; ++u) {
      axy[r][u] += __shfl_xor(axy[r][u], 1); axy[r][u] += __shfl_xor(axy[r][u], 2);
      axx[r][u] += __shfl_xor(axx[r][u], 1); axx[r][u] += __shfl_xor(axx[r][u], 2);
      ayy[r][u] += __shfl_xor(ayy[r][u], 1); ayy[r][u] += __shfl_xor(ayy[r][u], 2);
    }
  }
  // ---- z over the 16 column-group lanes (lane bits 0..3) ----
  #pragma unroll
  for (int d = 1; d <= 8; d <<= 1) {
    #pragma unroll
    for (int q = 0; q < 4; ++q) {
      zx[q] += __shfl_xor(zx[q], d);
      zy[q] += __shfl_xor(zy[q], d);
    }
  }

  if (A.atomicMode) {
    double* fin = A.finalG + (size_t)p * 800;
    if (s == 0) {
      #pragma unroll
      for (int r = 0; r < 4; ++r) {
        #pragma unroll
        for (int u = 0; u < 4; ++u) {
          const int ib = (4 * ti + r) * 16 + 4 * tk + u;
          atomicAdd(&fin[ib],       (double)axy[r][u]);
          atomicAdd(&fin[256 + ib], (double)axx[r][u]);
          atomicAdd(&fin[512 + ib], (double)ayy[r][u]);
        }
      }
    }
    if (cl == 0) {
      #pragma unroll
      for (int q = 0; q < 4; ++q) {
        atomicAdd(&fin[768 + 4 * h + q], (double)zx[q]);
        atomicAdd(&fin[784 + 4 * h + q], (double)zy[q]);
      }
    }
    return;
  }

  // ---- combine the block's 2 waves through wave1's (now idle) buffer ----
  float* outB = sE[1];
  if (w == 1) {
    if (s == 0) {
      #pragma unroll
      for (int r = 0; r < 4; ++r) {
        const int ib = (4 * ti + r) * 16 + 4 * tk;
        *reinterpret_cast<float4*>(outB + ib)       = make_float4(axy[r][0], axy[r][1], axy[r][2], axy[r][3]);
        *reinterpret_cast<float4*>(outB + 256 + ib) = make_float4(axx[r][0], axx[r][1], axx[r][2], axx[r][3]);
        *reinterpret_cast<float4*>(outB + 512 + ib) = make_float4(ayy[r][0], ayy[r][1], ayy[r][2], ayy[r][3]);
      }
    }
    if (cl == 0) {
      *reinterpret_cast<float4*>(outB + 768 + 4 * h) = make_float4(zx[0], zx[1], zx[2], zx[3]);
      *reinterpret_cast<float4*>(outB + 784 + 4 * h) = make_float4(zy[0], zy[1], zy[2], zy[3]);
    }
  }
  __syncthreads();   // only barrier in the kernel
  if (w == 0) {
    float* dst = A.partial + (size_t)bid * 800;   // contiguous per block
    if (s == 0) {
      #pragma unroll
      for (int r = 0; r < 4; ++r) {
        const int ib = (4 * ti + r) * 16 + 4 * tk;
        float4 o0 = *reinterpret_cast<const float4*>(outB + ib);
        float4 o1 = *reinterpret_cast<const float4*>(outB + 256 + ib);
        float4 o2 = *reinterpret_cast<const float4*>(outB + 512 + ib);
        o0.x += axy[r][0]; o0.y += axy[r][1]; o0.z += axy[r][2]; o0.w += axy[r][3];
        o1.x += axx[r][0]; o1.y += axx[r][1]; o1.z += axx[r][2]; o1.w += axx[r][3];
        o2.x += ayy[r][0]; o2.y += ayy[r][1]; o2.z += ayy[r][2]; o2.w += ayy[r][3];
        *reinterpret_cast<float4*>(dst + ib)       = o0;
        *reinterpret_cast<float4*>(dst + 256 + ib) = o1;
        *reinterpret_cast<float4*>(dst + 512 + ib) = o2;
      }
    }
    if (cl == 0) {
      float4 z0 = *reinterpret_cast<const float4*>(outB + 768 + 4 * h);
      float4 z1 = *reinterpret_cast<const float4*>(outB + 784 + 4 * h);
      z0.x += zx[0]; z0.y += zx[1]; z0.z += zx[2]; z0.w += zx[3];
      z1.x += zy[0]; z1.y += zy[1]; z1.z += zy[2]; z1.w += zy[3];
      *reinterpret_cast<float4*>(dst + 768 + 4 * h) = z0;
      *reinterpret_cast<float4*>(dst + 784 + 4 * h) = z1;
    }
  }
}

// 16 partial-rows per block, fully coalesced contiguous reads (3200 B rows),
// fp64 register accumulation, one atomicAdd per value.
__global__ __launch_bounds__(256) void reduce_kernel(const float* __restrict__ partial,
                                                     double* __restrict__ finalG,
                                                     int nb0, int nb1, int nb2) {
  const int c0 = (nb0 + 15) >> 4, c1 = (nb1 + 15) >> 4;
  const int b = blockIdx.x;
  int p, r0, pstart, cnt;
  if (b < c0)           { p = 0; r0 = b << 4;            pstart = 0;         cnt = nb0; }
  else if (b < c0 + c1) { p = 1; r0 = (b - c0) << 4;     pstart = nb0;       cnt = nb1; }
  else                  { p = 2; r0 = (b - c0 - c1) << 4; pstart = nb0 + nb1; cnt = nb2; }
  const int rows = min(16, cnt - r0);
  const float* src = partial + (size_t)(pstart + r0) * 800;
  const int tt = threadIdx.x;
  double s0 = 0.0, s1 = 0.0, s2 = 0.0, s3 = 0.0;
  #pragma unroll 1
  for (int r = 0; r < rows; ++r) {
    const float* row = src + (size_t)r * 800;
    s0 += (double)row[tt];
    s1 += (double)row[tt + 256];
    s2 += (double)row[tt + 512];
    if (tt < 32) s3 += (double)row[768 + tt];
  }
  double* fin = finalG + (size_t)p * 800;
  atomicAdd(&fin[tt], s0);
  atomicAdd(&fin[tt + 256], s1);
  atomicAdd(&fin[tt + 512], s2);
  if (tt < 32) atomicAdd(&fin[768 + tt], s3);
}

__device__ __forceinline__ float expm1_poly(float d) {
  float pp = 1.0f / 120.0f;
  pp = fmaf(pp, d, 1.0f / 24.0f);
  pp = fmaf(pp, d, 1.0f / 6.0f);
  pp = fmaf(pp, d, 0.5f);
  return fmaf(d * d, pp, d);
}
__device__ __forceinline__ float log1p_poly(float w) {
  float pp = -1.0f / 6.0f;
  pp = fmaf(pp, w, 1.0f / 5.0f);
  pp = fmaf(pp, w, -1.0f / 4.0f);
  pp = fmaf(pp, w, 1.0f / 3.0f);
  pp = fmaf(pp, w, -0.5f);
  return fmaf(w * w, pp, w);
}

// 6 waves in ONE block: wave 2p = (f,g) chains of pair p ; 2p+1 = (a,b)
// self chains. finalize folded in after __syncthreads (one fewer dispatch).
__global__ __launch_bounds__(384) void sinkhorn_kernel(const double* __restrict__ finalG,
                                                       float* __restrict__ out, EpsList E) {
  const int grp  = threadIdx.x >> 6;
  const int p    = grp >> 1;
  const int half = grp & 1;
  const int lane = threadIdx.x & 63;
  const int pot  = lane >> 5;
  const int i    = (lane >> 1) & 15;
  const int jh   = lane & 1;
  const double* G = finalG + p * 800;

  float Crow[8];
  #pragma unroll
  for (int jj = 0; jj < 8; ++jj) {
    const int j = jh * 8 + jj;
    double Cv;
    if (half == 0) {
      const int r = (pot == 0) ? i : j;
      const int c = (pot == 0) ? j : i;
      const double zr = G[768 + r], zc = G[784 + c];
      const double sr = G[256 + 17 * r] / (zr * zr);
      const double sc = G[512 + 17 * c] / (zc * zc);
      Cv = 0.5 * (sr + sc) - G[16 * r + c] / (zr * zc);
    } else if (pot == 0) {
      const double zi_ = G[768 + i], zj_ = G[768 + j];
      const double si_ = G[256 + 17 * i] / (zi_ * zi_);
      const double sj_ = G[256 + 17 * j] / (zj_ * zj_);
      Cv = 0.5 * (si_ + sj_) - G[256 + 16 * i + j] / (zi_ * zj_);
    } else {
      const double zi_ = G[784 + i], zj_ = G[784 + j];
      const double si_ = G[512 + 17 * i] / (zi_ * zi_);
      const double sj_ = G[512 + 17 * j] / (zj_ * zj_);
      Cv = 0.5 * (si_ + sj_) - G[512 + 16 * i + j] / (zi_ * zj_);
    }
    Crow[jj] = (float)Cv;
  }

  const int srcBase = (half == 0) ? ((pot == 0) ? 32 : 0)
                                  : ((pot == 0) ? 0 : 32);
  float h = 0.0f;

  #pragma unroll 1
  for (int n = 0; n < NSTEP; ++n) {
    const float eps  = E.e[n];
    const float inve = 1.0f / eps;
    float q = 0.0f;
    #pragma unroll
    for (int jj = 0; jj < 8; ++jj) {
      const float hj = __shfl(h, srcBase + 2 * (jh * 8 + jj));
      q += expm1_poly((hj - Crow[jj]) * inve);
    }
    q += __shfl_xor(q, 1);
    const float val = -eps * log1p_poly(q * (1.0f / 16.0f));
    h = 0.5f * (h + val);
  }
  {
    const float eps  = 0.0025f;
    const float inve = 1.0f / eps;
    float q = 0.0f;
    #pragma unroll
    for (int jj = 0; jj < 8; ++jj) {
      const float hj = __shfl(h, srcBase + 2 * (jh * 8 + jj));
      q += expm1_poly((hj - Crow[jj]) * inve);
    }
    q += __shfl_xor(q, 1);
    h = -eps * log1p_poly(q * (1.0f / 16.0f));
  }
  float sAcc = h;
  #pragma unroll
  for (int d = 1; d <= 32; d <<= 1) sAcc += __shfl_xor(sAcc, d);

  __shared__ double res[6];
  if (lane == 0) res[grp] = (double)(sAcc * (1.0f / 32.0f));
  __syncthreads();
  if (threadIdx.x == 0) {
    const double v = (res[0] - res[1]) + (res[2] - res[3]) + (res[4] - res[5]);
    out[0] = (float)(v / 3.0);
  }
}

extern "C" void kernel_launch(void* const* d_in, const int* in_sizes, int n_in,
                              void* d_out, int out_size, void* d_ws, size_t ws_size,
                              hipStream_t stream) {
  (void)n_in; (void)out_size;
  int idx[6] = {0, 1, 2, 3, 4, 5};
  for (int a = 1; a < 6; ++a) {
    const int key = idx[a];
    int b = a - 1;
    while (b >= 0 && in_sizes[idx[b]] < in_sizes[key]) { idx[b + 1] = idx[b]; --b; }
    idx[b + 1] = key;
  }

  const float* xs[3]; const float* ys[3]; int Ms[3]; int nb[3];
  for (int p = 0; p < 3; ++p) {
    xs[p] = (const float*)d_in[idx[2 * p]];
    ys[p] = (const float*)d_in[idx[2 * p + 1]];
    Ms[p] = in_sizes[idx[2 * p]] / 16;
    nb[p] = Ms[p] / COLS_PER_BLOCK;
  }
  const int totalBlocks = nb[0] + nb[1] + nb[2];

  const size_t partialBytes = (size_t)totalBlocks * 800 * sizeof(float);
  const size_t finalBytes   = (size_t)2400 * sizeof(double);
  const bool partialMode    = (ws_size >= partialBytes + finalBytes);

  char* wsb      = (char*)d_ws;
  float* partial = partialMode ? (float*)wsb : nullptr;
  double* finalG = (double*)(wsb + (partialMode ? partialBytes : 0));

  hipMemsetAsync(finalG, 0, finalBytes, stream);

  GramArgs A;
  A.x0 = xs[0]; A.y0 = ys[0];
  A.x1 = xs[1]; A.y1 = ys[1];
  A.x2 = xs[2]; A.y2 = ys[2];
  A.M0 = Ms[0]; A.M1 = Ms[1]; A.M2 = Ms[2];
  A.bs1 = nb[0]; A.bs2 = nb[0] + nb[1]; A.bsTot = totalBlocks;
  A.partial = partial; A.finalG = finalG;
  A.atomicMode = partialMode ? 0 : 1;

  gram_kernel<<<dim3(totalBlocks), dim3(TPB), 0, stream>>>(A);
  if (partialMode) {
    const int rb = ((nb[0] + 15) / 16) + ((nb[1] + 15) / 16) + ((nb[2] + 15) / 16);
    reduce_kernel<<<dim3(rb), dim3(256), 0, stream>>>(partial, finalG, nb[0], nb[1], nb[2]);
  }

  EpsList E;
  const double base = 0.95 * 0.95;
  for (int n = 0; n < NSTEP; ++n) {
    double v = pow(base, (double)n);
    if (v < 0.0025) v = 0.0025;
    E.e[n] = (float)v;
  }
  sinkhorn_kernel<<<dim3(1), dim3(384), 0, stream>>>(finalG, (float*)d_out, E);
}